// Round 3
// baseline (574.370 us; speedup 1.0000x reference)
//
#include <hip/hip_runtime.h>
#include <hip/hip_fp16.h>

#define N_USERS 100000
#define N_ITEMS 50000
#define N_TOPICS 1000
#define N_NODES (N_USERS + N_ITEMS + N_TOPICS)   // 151000
#define DIM 64
#define NNZ 4000000
#define BATCH 16384

#define BROWS 128                                 // rows per bucket
#define NB ((N_NODES + BROWS - 1) / BROWS)        // 1180 buckets
#define NPART 512                                 // partition blocks
#define CHUNK ((NNZ + NPART - 1) / NPART)         // 7813 edges per block
#define SEGCAP 4608                               // LDS seg capacity (36 KB)

// cv entry: (qval14 << 18) | col18 ; val = qval * (1/16384)
#define QSCALE 16384.0f
#define QINV   6.103515625e-05f                   // 1/16384

// x tables are stored as TWO PLANES of 32 dims each (16 half2 per row):
// plane p, row r lives at x2[((size_t)p * N_NODES + r) * 16 + d], d in [0,16).
#define PSTRIDE ((size_t)N_NODES * 16)            // half2 units per plane

// ---------------------------------------------------------------------------
// Build X0 = concat(user_w, item_w, topic_w) in FP16, plane layout.
// tid covers (node, q) with q in [0,16): dims 4q..4q+3.
// ---------------------------------------------------------------------------
__global__ void concat_init(const float4* __restrict__ uw,
                            const float4* __restrict__ iw,
                            const float4* __restrict__ tw,
                            __half2* __restrict__ x0) {
    int tid = blockIdx.x * blockDim.x + threadIdx.x;   // node*16 + q
    const int total = N_NODES * (DIM / 4);
    if (tid >= total) return;
    int node = tid >> 4;
    int q = tid & 15;
    float4 v;
    if (node < N_USERS)                v = uw[node * 16 + q];
    else if (node < N_USERS + N_ITEMS) v = iw[(node - N_USERS) * 16 + q];
    else                               v = tw[(node - N_USERS - N_ITEMS) * 16 + q];
    int plane = q >> 3;            // dims >= 32 -> plane 1
    int dq = q & 7;                // half2 pair index within plane
    __half2* dst = x0 + ((size_t)plane * N_NODES + node) * 16 + dq * 2;
    dst[0] = __floats2half2_rn(v.x, v.y);
    dst[1] = __floats2half2_rn(v.z, v.w);
}

// ---------------------------------------------------------------------------
// Partition phase 1: per-block bucket histogram of its contiguous chunk.
// ---------------------------------------------------------------------------
__global__ void __launch_bounds__(1024)
part_count(const int* __restrict__ row, int* __restrict__ hcnt) {
    __shared__ int h[NB];
    const int g = blockIdx.x;
    const int t = threadIdx.x;
    for (int i = t; i < NB; i += 1024) h[i] = 0;
    __syncthreads();
    int e0 = g * CHUNK;
    int e1 = e0 + CHUNK; if (e1 > NNZ) e1 = NNZ;
    for (int e = e0 + t; e < e1; e += 1024) {
        int r = __builtin_nontemporal_load(&row[e]);
        atomicAdd(&h[r >> 7], 1);
    }
    __syncthreads();
    int* dst = hcnt + (size_t)g * NB;
    for (int i = t; i < NB; i += 1024) dst[i] = h[i];
}

// ---------------------------------------------------------------------------
// Partition phase 2a: per-bucket exclusive scan across the NPART blocks.
// ---------------------------------------------------------------------------
__global__ void part_scanA(int* __restrict__ hcnt, int* __restrict__ bcnt) {
    int b = blockIdx.x * 4 + (threadIdx.x >> 6);
    int lane = threadIdx.x & 63;
    if (b >= NB) return;
    int carry = 0;
    for (int base = 0; base < NPART; base += 64) {
        int g = base + lane;
        int v = hcnt[(size_t)g * NB + b];
        int x = v;
        #pragma unroll
        for (int off = 1; off < 64; off <<= 1) {
            int y = __shfl_up(x, off, 64);
            if (lane >= off) x += y;
        }
        int tot = __shfl(x, 63, 64);
        hcnt[(size_t)g * NB + b] = carry + x - v;
        carry += tot;
    }
    if (lane == 0) bcnt[b] = carry;
}

// ---------------------------------------------------------------------------
// Partition phase 2b: exclusive scan over NB bucket totals (single block).
// ---------------------------------------------------------------------------
__global__ void part_scanB(const int* __restrict__ bcnt,
                           int* __restrict__ bptr,
                           int* __restrict__ rowptr) {
    __shared__ int wsum[16];
    __shared__ int carry_s;
    const int t = threadIdx.x;
    const int lane = t & 63;
    const int wid = t >> 6;
    if (t == 0) carry_s = 0;
    __syncthreads();
    for (int base = 0; base < NB; base += 1024) {
        int i = base + t;
        int v = (i < NB) ? bcnt[i] : 0;
        int x = v;
        #pragma unroll
        for (int off = 1; off < 64; off <<= 1) {
            int y = __shfl_up(x, off, 64);
            if (lane >= off) x += y;
        }
        if (lane == 63) wsum[wid] = x;
        __syncthreads();
        int wbase = 0;
        for (int w = 0; w < wid; ++w) wbase += wsum[w];
        int excl = carry_s + wbase + (x - v);
        if (i < NB) bptr[i] = excl;
        __syncthreads();
        if (t == 1023) carry_s = excl + v;
        __syncthreads();
    }
    if (t == 0) { bptr[NB] = NNZ; rowptr[N_NODES] = NNZ; }
}

// ---------------------------------------------------------------------------
// Partition phase 3: atomic-free scatter via per-(block,bucket) offsets.
// ---------------------------------------------------------------------------
__global__ void __launch_bounds__(1024)
part_scatter(const int* __restrict__ row,
             const int* __restrict__ col,
             const float* __restrict__ vals,
             const int* __restrict__ hcnt,
             const int* __restrict__ bptr,
             int2* __restrict__ cvtmp) {
    __shared__ int cur[NB];
    const int g = blockIdx.x;
    const int t = threadIdx.x;
    const int* hoff = hcnt + (size_t)g * NB;
    for (int i = t; i < NB; i += 1024) cur[i] = bptr[i] + hoff[i];
    __syncthreads();
    int e0 = g * CHUNK;
    int e1 = e0 + CHUNK; if (e1 > NNZ) e1 = NNZ;
    for (int e = e0 + t; e < e1; e += 1024) {
        int r = __builtin_nontemporal_load(&row[e]);
        int c = __builtin_nontemporal_load(&col[e]);
        float v = __builtin_nontemporal_load(&vals[e]);
        int p = atomicAdd(&cur[r >> 7], 1);
        cvtmp[p] = make_int2(((r & (BROWS - 1)) << 18) | c, __float_as_int(v));
    }
}

// ---------------------------------------------------------------------------
// Bucket-local counting sort -> row-sorted CSR (cv, packed 4B) + rowptr.
// ---------------------------------------------------------------------------
__global__ void __launch_bounds__(256)
bucket_sort(const int* __restrict__ bptr,
            const long long* __restrict__ cvtmp,
            unsigned int* __restrict__ cv,
            int* __restrict__ rowptr) {
    __shared__ int2 seg[SEGCAP];     // 36 KB
    __shared__ int cnt[BROWS];
    __shared__ int cur[BROWS];
    const int t = threadIdx.x;
    const int b = blockIdx.x;
    const int beg = bptr[b];
    const int end = bptr[b + 1];
    const int n = end - beg;

    for (int i = t; i < BROWS; i += 256) cnt[i] = 0;
    const bool lds_path = (n <= SEGCAP);

    if (lds_path) {
        for (int j = t; j < n; j += 256) {
            long long e = __builtin_nontemporal_load(&cvtmp[beg + j]);
            seg[j] = make_int2((int)e, (int)(e >> 32));
        }
    }
    __syncthreads();

    // pass 1: per-row counts
    if (lds_path) {
        for (int j = t; j < n; j += 256)
            atomicAdd(&cnt[(seg[j].x >> 18) & (BROWS - 1)], 1);
    } else {
        for (int j = beg + t; j < end; j += 256) {
            long long e = cvtmp[j];
            atomicAdd(&cnt[((int)e >> 18) & (BROWS - 1)], 1);
        }
    }
    __syncthreads();

    // exclusive scan of 128 counts on wave 0; also emit rowptr
    if (t < 64) {
        int lane = t;
        int v0 = cnt[lane];
        int v1 = cnt[64 + lane];
        int x0 = v0;
        #pragma unroll
        for (int off = 1; off < 64; off <<= 1) {
            int y = __shfl_up(x0, off, 64);
            if (lane >= off) x0 += y;
        }
        int tot0 = __shfl(x0, 63, 64);
        int x1 = v1;
        #pragma unroll
        for (int off = 1; off < 64; off <<= 1) {
            int y = __shfl_up(x1, off, 64);
            if (lane >= off) x1 += y;
        }
        x1 += tot0;
        int e0 = x0 - v0;
        int e1 = x1 - v1;
        cur[lane] = e0;
        cur[64 + lane] = e1;
        int rowbase = b * BROWS;
        if (rowbase + lane < N_NODES)      rowptr[rowbase + lane] = beg + e0;
        if (rowbase + 64 + lane < N_NODES) rowptr[rowbase + 64 + lane] = beg + e1;
    }
    __syncthreads();

    // pass 2: scatter into row-sorted order; pack (qval<<18)|col
    if (lds_path) {
        for (int j = t; j < n; j += 256) {
            int2 e = seg[j];
            int p = atomicAdd(&cur[(e.x >> 18) & (BROWS - 1)], 1);
            float v = __int_as_float(e.y);
            unsigned int qv = (unsigned int)(v * QSCALE + 0.5f);
            if (qv > 16383u) qv = 16383u;
            cv[beg + p] = (qv << 18) | (unsigned int)(e.x & 0x3FFFF);
        }
    } else {
        for (int j = beg + t; j < end; j += 256) {
            long long e = cvtmp[j];
            int lo = (int)e;
            float v = __int_as_float((int)(e >> 32));
            int p = atomicAdd(&cur[(lo >> 18) & (BROWS - 1)], 1);
            unsigned int qv = (unsigned int)(v * QSCALE + 0.5f);
            if (qv > 16383u) qv = 16383u;
            cv[beg + p] = (qv << 18) | (unsigned int)(lo & 0x3FFFF);
        }
    }
}

// ---------------------------------------------------------------------------
// SpMM over CSR, HALF-DIM PASS (32 dims = one 9.67 MB plane).
// One wave per row; 4 quarters x 16 lanes; quarter q processes edges
// beg+q, stride 4; each gather is 64 B (one cache line). Plain cv loads
// (L1-served line reuse); nontemporal y store (write-once, keep L2 for x),
// bit-cast to uint (builtin rejects __half2*).
// ---------------------------------------------------------------------------
__global__ void spmm_csr(const int* __restrict__ rowptr,
                         const unsigned int* __restrict__ cv,
                         const __half2* __restrict__ xp,   // plane base, in
                         __half2* __restrict__ yp) {       // plane base, out
    int blk = blockIdx.x;
    int bucket = (blk >> 8) * 8 + (blk & 7);
    int sub = (blk & 255) >> 3;
    int r = bucket * BROWS + sub * 4 + (threadIdx.x >> 6);
    if (r >= N_NODES) return;
    int lane = threadIdx.x & 63;
    int qt = lane >> 4;          // quarter 0..3
    int d = lane & 15;
    int beg = rowptr[r];
    int n = rowptr[r + 1] - beg;
    const unsigned int* cvb = cv + beg;
    float ax = 0.0f, ay = 0.0f;
    int base = 0;
    for (; base + 32 <= n; base += 32) {     // 8 edges per quarter
        unsigned int u[8];
        __half2 h[8];
        #pragma unroll
        for (int k = 0; k < 8; ++k) u[k] = cvb[base + qt + 4 * k];
        #pragma unroll
        for (int k = 0; k < 8; ++k) h[k] = xp[(size_t)(u[k] & 0x3FFFF) * 16 + d];
        #pragma unroll
        for (int k = 0; k < 8; ++k) {
            float2 f = __half22float2(h[k]);
            float v = (float)(u[k] >> 18) * QINV;
            ax = fmaf(v, f.x, ax); ay = fmaf(v, f.y, ay);
        }
    }
    for (; base + 16 <= n; base += 16) {     // 4 edges per quarter
        unsigned int u[4];
        __half2 h[4];
        #pragma unroll
        for (int k = 0; k < 4; ++k) u[k] = cvb[base + qt + 4 * k];
        #pragma unroll
        for (int k = 0; k < 4; ++k) h[k] = xp[(size_t)(u[k] & 0x3FFFF) * 16 + d];
        #pragma unroll
        for (int k = 0; k < 4; ++k) {
            float2 f = __half22float2(h[k]);
            float v = (float)(u[k] >> 18) * QINV;
            ax = fmaf(v, f.x, ax); ay = fmaf(v, f.y, ay);
        }
    }
    for (; base + 4 <= n; base += 4) {       // 1 edge per quarter
        unsigned int u = cvb[base + qt];
        float2 f = __half22float2(xp[(size_t)(u & 0x3FFFF) * 16 + d]);
        float v = (float)(u >> 18) * QINV;
        ax = fmaf(v, f.x, ax); ay = fmaf(v, f.y, ay);
    }
    int rem = n - base;                      // 0..3
    if (qt < rem) {
        unsigned int u = cvb[base + qt];
        float2 f = __half22float2(xp[(size_t)(u & 0x3FFFF) * 16 + d]);
        float v = (float)(u >> 18) * QINV;
        ax = fmaf(v, f.x, ax); ay = fmaf(v, f.y, ay);
    }
    // reduce across the 4 quarters
    ax += __shfl_down(ax, 16, 64);
    ay += __shfl_down(ay, 16, 64);
    ax += __shfl_down(ax, 32, 64);
    ay += __shfl_down(ay, 32, 64);
    if (lane < 16) {
        __half2 o = __floats2half2_rn(ax, ay);
        unsigned int ob;
        __builtin_memcpy(&ob, &o, 4);
        __builtin_nontemporal_store(ob,
            (unsigned int*)&yp[(size_t)r * 16 + d]);
    }
}

// ---------------------------------------------------------------------------
// Layer-3 SpMM restricted to batch rows, half-dim pass; fp32 accumulate
// straight into ACCB (float2 RMW at dims plane*32 + 2d).
// ---------------------------------------------------------------------------
__global__ void spmm_batch(const int* __restrict__ rowptr,
                           const unsigned int* __restrict__ cv,
                           const __half2* __restrict__ xp,   // plane base, in
                           const int* __restrict__ users,
                           const int* __restrict__ items,
                           float* __restrict__ accb,
                           int plane) {
    int b = blockIdx.x * 4 + (threadIdx.x >> 6);
    if (b >= 2 * BATCH) return;
    int lane = threadIdx.x & 63;
    int qt = lane >> 4;
    int d = lane & 15;
    int r = (b < BATCH) ? users[b] : (N_USERS + items[b - BATCH]);
    int beg = rowptr[r];
    int n = rowptr[r + 1] - beg;
    const unsigned int* cvb = cv + beg;
    float ax = 0.0f, ay = 0.0f;
    int base = 0;
    for (; base + 32 <= n; base += 32) {
        unsigned int u[8];
        __half2 h[8];
        #pragma unroll
        for (int k = 0; k < 8; ++k) u[k] = cvb[base + qt + 4 * k];
        #pragma unroll
        for (int k = 0; k < 8; ++k) h[k] = xp[(size_t)(u[k] & 0x3FFFF) * 16 + d];
        #pragma unroll
        for (int k = 0; k < 8; ++k) {
            float2 f = __half22float2(h[k]);
            float v = (float)(u[k] >> 18) * QINV;
            ax = fmaf(v, f.x, ax); ay = fmaf(v, f.y, ay);
        }
    }
    for (; base + 16 <= n; base += 16) {
        unsigned int u[4];
        __half2 h[4];
        #pragma unroll
        for (int k = 0; k < 4; ++k) u[k] = cvb[base + qt + 4 * k];
        #pragma unroll
        for (int k = 0; k < 4; ++k) h[k] = xp[(size_t)(u[k] & 0x3FFFF) * 16 + d];
        #pragma unroll
        for (int k = 0; k < 4; ++k) {
            float2 f = __half22float2(h[k]);
            float v = (float)(u[k] >> 18) * QINV;
            ax = fmaf(v, f.x, ax); ay = fmaf(v, f.y, ay);
        }
    }
    for (; base + 4 <= n; base += 4) {
        unsigned int u = cvb[base + qt];
        float2 f = __half22float2(xp[(size_t)(u & 0x3FFFF) * 16 + d]);
        float v = (float)(u >> 18) * QINV;
        ax = fmaf(v, f.x, ax); ay = fmaf(v, f.y, ay);
    }
    int rem = n - base;
    if (qt < rem) {
        unsigned int u = cvb[base + qt];
        float2 f = __half22float2(xp[(size_t)(u & 0x3FFFF) * 16 + d]);
        float v = (float)(u >> 18) * QINV;
        ax = fmaf(v, f.x, ax); ay = fmaf(v, f.y, ay);
    }
    ax += __shfl_down(ax, 16, 64);
    ay += __shfl_down(ay, 16, 64);
    ax += __shfl_down(ax, 32, 64);
    ay += __shfl_down(ay, 32, 64);
    if (lane < 16) {
        float2* a2 = (float2*)(accb + (size_t)b * 64 + plane * 32 + 2 * d);
        float2 o = *a2;
        o.x += ax; o.y += ay;
        *a2 = o;
    }
}

// ---------------------------------------------------------------------------
// Batch accumulator init (fp32 weights -> fp32 ACCB; layer-0 term exact).
// ---------------------------------------------------------------------------
__global__ void batch_init(const float4* __restrict__ uw,
                           const float4* __restrict__ iw,
                           const int* __restrict__ users,
                           const int* __restrict__ items,
                           float4* __restrict__ accb) {
    int tid = blockIdx.x * blockDim.x + threadIdx.x;   // row*16 + q
    const int total = 2 * BATCH * (DIM / 4);
    if (tid >= total) return;
    int r = tid >> 4;
    int q = tid & 15;
    float4 v;
    if (r < BATCH) v = uw[(size_t)users[r] * 16 + q];
    else           v = iw[(size_t)items[r - BATCH] * 16 + q];
    accb[tid] = v;
}

// ---------------------------------------------------------------------------
// Batch accumulator add from fp16 node table (layers 1,2) — plane layout.
// ---------------------------------------------------------------------------
__global__ void batch_add(const __half2* __restrict__ emb2,
                          const int* __restrict__ users,
                          const int* __restrict__ items,
                          float4* __restrict__ accb) {
    int tid = blockIdx.x * blockDim.x + threadIdx.x;
    const int total = 2 * BATCH * (DIM / 4);
    if (tid >= total) return;
    int r = tid >> 4;
    int q = tid & 15;
    int node = (r < BATCH) ? users[r] : (N_USERS + items[r - BATCH]);
    int plane = q >> 3;
    int dq = q & 7;
    const __half2* e2 = emb2 + ((size_t)plane * N_NODES + node) * 16 + dq * 2;
    float2 lo = __half22float2(e2[0]);
    float2 hi = __half22float2(e2[1]);
    float4 a = accb[tid];
    a.x += lo.x; a.y += lo.y; a.z += hi.x; a.w += hi.y;
    accb[tid] = a;
}

// ---------------------------------------------------------------------------
// Final dot: out[b] = (accb[b] . accb[BATCH+b]) / 16
// ---------------------------------------------------------------------------
__global__ void final_dot(const float* __restrict__ accb,
                          float* __restrict__ out) {
    int b = blockIdx.x * 4 + (threadIdx.x >> 6);
    int lane = threadIdx.x & 63;
    if (b >= BATCH) return;
    float pu = accb[(size_t)b * 64 + lane];
    float pi = accb[(size_t)(BATCH + b) * 64 + lane];
    float p = pu * pi;
    #pragma unroll
    for (int off = 32; off > 0; off >>= 1)
        p += __shfl_down(p, off, 64);
    if (lane == 0) out[b] = p * (1.0f / 16.0f);
}

extern "C" void kernel_launch(void* const* d_in, const int* in_sizes, int n_in,
                              void* d_out, int out_size, void* d_ws, size_t ws_size,
                              hipStream_t stream) {
    const float* uw   = (const float*)d_in[0];
    const float* iw   = (const float*)d_in[1];
    const float* tw   = (const float*)d_in[2];
    const float* vals = (const float*)d_in[3];
    const int*   row  = (const int*)d_in[4];
    const int*   col  = (const int*)d_in[5];
    const int*   users= (const int*)d_in[6];
    const int*   items= (const int*)d_in[7];
    float* out = (float*)d_out;

    // ---- workspace layout (no aliasing; ~98 MB total) ----
    char* ws = (char*)d_ws;
    const size_t NODE_F = (size_t)N_NODES * DIM;       // 9,664,000 elements
    __half* A     = (__half*)ws; ws += NODE_F * 2;     // 19.33 MB (2 planes)
    __half* B     = (__half*)ws; ws += NODE_F * 2;     // 19.33 MB (2 planes)
    float* ACCB   = (float*)ws;  ws += (size_t)2 * BATCH * DIM * 4;
    int*   bcnt   = (int*)ws;    ws += (size_t)NB * 4;
    int*   bptr   = (int*)ws;    ws += (size_t)(NB + 1) * 4;
    int*   rowptr = (int*)ws;    ws += (size_t)(N_NODES + 1) * 4;
    int*   hcnt   = (int*)ws;    ws += (size_t)NPART * NB * 4;   // 2.42 MB
    unsigned int* cv = (unsigned int*)ws; ws += (size_t)NNZ * 4; // 16 MB packed
    int2*  cvtmp  = (int2*)ws;   ws += (size_t)NNZ * 8;          // 32 MB

    const int node_v4  = N_NODES * (DIM / 4);
    const int batch_v4 = 2 * BATCH * (DIM / 4);

    __half2* A2 = (__half2*)A;
    __half2* B2 = (__half2*)B;

    // ---- layer-0 embedding (fp16, plane layout) + batch acc init (fp32) ----
    concat_init<<<(node_v4 + 255) / 256, 256, 0, stream>>>(
        (const float4*)uw, (const float4*)iw, (const float4*)tw, A2);
    batch_init<<<(batch_v4 + 255) / 256, 256, 0, stream>>>(
        (const float4*)uw, (const float4*)iw, users, items, (float4*)ACCB);

    // ---- atomic-free bucketed partition + bucket-local sort -> CSR ----
    part_count<<<NPART, 1024, 0, stream>>>(row, hcnt);
    part_scanA<<<(NB + 3) / 4, 256, 0, stream>>>(hcnt, bcnt);
    part_scanB<<<1, 1024, 0, stream>>>(bcnt, bptr, rowptr);
    part_scatter<<<NPART, 1024, 0, stream>>>(row, col, vals, hcnt, bptr, cvtmp);
    bucket_sort<<<NB, 256, 0, stream>>>(bptr, (const long long*)cvtmp, cv, rowptr);

    // ---- layers 1,2: full SpMM as two half-dim passes each ----
    const int spmm_blocks = ((NB + 7) / 8) * 256;   // 148*256 = 37888
    // layer 1: A -> B
    spmm_csr<<<spmm_blocks, 256, 0, stream>>>(rowptr, cv, A2, B2);
    spmm_csr<<<spmm_blocks, 256, 0, stream>>>(rowptr, cv, A2 + PSTRIDE, B2 + PSTRIDE);
    batch_add<<<(batch_v4 + 255) / 256, 256, 0, stream>>>(
        B2, users, items, (float4*)ACCB);
    // layer 2: B -> A
    spmm_csr<<<spmm_blocks, 256, 0, stream>>>(rowptr, cv, B2, A2);
    spmm_csr<<<spmm_blocks, 256, 0, stream>>>(rowptr, cv, B2 + PSTRIDE, A2 + PSTRIDE);
    batch_add<<<(batch_v4 + 255) / 256, 256, 0, stream>>>(
        A2, users, items, (float4*)ACCB);
    // layer 3: batch rows only, two half-dim passes
    spmm_batch<<<(2 * BATCH + 3) / 4, 256, 0, stream>>>(
        rowptr, cv, A2, users, items, ACCB, 0);
    spmm_batch<<<(2 * BATCH + 3) / 4, 256, 0, stream>>>(
        rowptr, cv, A2 + PSTRIDE, users, items, ACCB, 1);

    final_dot<<<(BATCH + 3) / 4, 256, 0, stream>>>(ACCB, out);
}

// Round 5
// 442.698 us; speedup vs baseline: 1.2974x; 1.2974x over previous
//
#include <hip/hip_runtime.h>
#include <hip/hip_fp16.h>

#define N_USERS 100000
#define N_ITEMS 50000
#define N_TOPICS 1000
#define N_NODES (N_USERS + N_ITEMS + N_TOPICS)   // 151000
#define DIM 64
#define NNZ 4000000
#define BATCH 16384

#define BROWS 128                                 // rows per bucket
#define NB ((N_NODES + BROWS - 1) / BROWS)        // 1180 buckets
#define NPART 256                                 // partition blocks (R4: 512->256, longer runs)
#define CHUNK ((NNZ + NPART - 1) / NPART)         // 15625 edges per block
#define SEGCAP 4608                               // LDS seg capacity (36 KB)

// cv entry: (qval14 << 18) | col18 ; val = qval * (1/16384)
#define QSCALE 16384.0f
#define QINV   6.103515625e-05f                   // 1/16384

// ---------------------------------------------------------------------------
// Build X0 = concat(user_w, item_w, topic_w) in FP16 (full-dim layout:
// row r at x2[r*32 + d], d in [0,32) half2 units).
// ---------------------------------------------------------------------------
__global__ void concat_init(const float4* __restrict__ uw,
                            const float4* __restrict__ iw,
                            const float4* __restrict__ tw,
                            __half2* __restrict__ x0) {
    int tid = blockIdx.x * blockDim.x + threadIdx.x;   // node*16 + q
    const int total = N_NODES * (DIM / 4);
    if (tid >= total) return;
    int node = tid >> 4;
    int q = tid & 15;
    float4 v;
    if (node < N_USERS)                v = uw[node * 16 + q];
    else if (node < N_USERS + N_ITEMS) v = iw[(node - N_USERS) * 16 + q];
    else                               v = tw[(node - N_USERS - N_ITEMS) * 16 + q];
    x0[tid * 2]     = __floats2half2_rn(v.x, v.y);
    x0[tid * 2 + 1] = __floats2half2_rn(v.z, v.w);
}

// ---------------------------------------------------------------------------
// Partition phase 1: per-block bucket histogram of its contiguous chunk.
// ---------------------------------------------------------------------------
__global__ void __launch_bounds__(1024)
part_count(const int* __restrict__ row, int* __restrict__ hcnt) {
    __shared__ int h[NB];
    const int g = blockIdx.x;
    const int t = threadIdx.x;
    for (int i = t; i < NB; i += 1024) h[i] = 0;
    __syncthreads();
    int e0 = g * CHUNK;
    int e1 = e0 + CHUNK; if (e1 > NNZ) e1 = NNZ;
    for (int e = e0 + t; e < e1; e += 1024) {
        int r = __builtin_nontemporal_load(&row[e]);
        atomicAdd(&h[r >> 7], 1);
    }
    __syncthreads();
    int* dst = hcnt + (size_t)g * NB;
    for (int i = t; i < NB; i += 1024) dst[i] = h[i];
}

// ---------------------------------------------------------------------------
// Partition phase 2a: per-bucket exclusive scan across the NPART blocks.
// ---------------------------------------------------------------------------
__global__ void part_scanA(int* __restrict__ hcnt, int* __restrict__ bcnt) {
    int b = blockIdx.x * 4 + (threadIdx.x >> 6);
    int lane = threadIdx.x & 63;
    if (b >= NB) return;
    int carry = 0;
    for (int base = 0; base < NPART; base += 64) {
        int g = base + lane;
        int v = hcnt[(size_t)g * NB + b];
        int x = v;
        #pragma unroll
        for (int off = 1; off < 64; off <<= 1) {
            int y = __shfl_up(x, off, 64);
            if (lane >= off) x += y;
        }
        int tot = __shfl(x, 63, 64);
        hcnt[(size_t)g * NB + b] = carry + x - v;
        carry += tot;
    }
    if (lane == 0) bcnt[b] = carry;
}

// ---------------------------------------------------------------------------
// Partition phase 2b: exclusive scan over NB bucket totals (single block).
// ---------------------------------------------------------------------------
__global__ void part_scanB(const int* __restrict__ bcnt,
                           int* __restrict__ bptr,
                           int* __restrict__ rowptr) {
    __shared__ int wsum[16];
    __shared__ int carry_s;
    const int t = threadIdx.x;
    const int lane = t & 63;
    const int wid = t >> 6;
    if (t == 0) carry_s = 0;
    __syncthreads();
    for (int base = 0; base < NB; base += 1024) {
        int i = base + t;
        int v = (i < NB) ? bcnt[i] : 0;
        int x = v;
        #pragma unroll
        for (int off = 1; off < 64; off <<= 1) {
            int y = __shfl_up(x, off, 64);
            if (lane >= off) x += y;
        }
        if (lane == 63) wsum[wid] = x;
        __syncthreads();
        int wbase = 0;
        for (int w = 0; w < wid; ++w) wbase += wsum[w];
        int excl = carry_s + wbase + (x - v);
        if (i < NB) bptr[i] = excl;
        __syncthreads();
        if (t == 1023) carry_s = excl + v;
        __syncthreads();
    }
    if (t == 0) { bptr[NB] = NNZ; rowptr[N_NODES] = NNZ; }
}

// ---------------------------------------------------------------------------
// Partition phase 3: atomic-free scatter via per-(block,bucket) offsets.
// NPART=256: per-(block,bucket) runs ~13.2 edges (~106 B) to cut the
// partial-line write amplification seen at NPART=512 (WRITE 110MB/32MB).
// ---------------------------------------------------------------------------
__global__ void __launch_bounds__(1024)
part_scatter(const int* __restrict__ row,
             const int* __restrict__ col,
             const float* __restrict__ vals,
             const int* __restrict__ hcnt,
             const int* __restrict__ bptr,
             int2* __restrict__ cvtmp) {
    __shared__ int cur[NB];
    const int g = blockIdx.x;
    const int t = threadIdx.x;
    const int* hoff = hcnt + (size_t)g * NB;
    for (int i = t; i < NB; i += 1024) cur[i] = bptr[i] + hoff[i];
    __syncthreads();
    int e0 = g * CHUNK;
    int e1 = e0 + CHUNK; if (e1 > NNZ) e1 = NNZ;
    for (int e = e0 + t; e < e1; e += 1024) {
        int r = __builtin_nontemporal_load(&row[e]);
        int c = __builtin_nontemporal_load(&col[e]);
        float v = __builtin_nontemporal_load(&vals[e]);
        int p = atomicAdd(&cur[r >> 7], 1);
        cvtmp[p] = make_int2(((r & (BROWS - 1)) << 18) | c, __float_as_int(v));
    }
}

// ---------------------------------------------------------------------------
// Bucket-local counting sort -> row-sorted CSR (cv, packed 4B) + rowptr.
// ---------------------------------------------------------------------------
__global__ void __launch_bounds__(256)
bucket_sort(const int* __restrict__ bptr,
            const long long* __restrict__ cvtmp,
            unsigned int* __restrict__ cv,
            int* __restrict__ rowptr) {
    __shared__ int2 seg[SEGCAP];     // 36 KB
    __shared__ int cnt[BROWS];
    __shared__ int cur[BROWS];
    const int t = threadIdx.x;
    const int b = blockIdx.x;
    const int beg = bptr[b];
    const int end = bptr[b + 1];
    const int n = end - beg;

    for (int i = t; i < BROWS; i += 256) cnt[i] = 0;
    const bool lds_path = (n <= SEGCAP);

    if (lds_path) {
        for (int j = t; j < n; j += 256) {
            long long e = __builtin_nontemporal_load(&cvtmp[beg + j]);
            seg[j] = make_int2((int)e, (int)(e >> 32));
        }
    }
    __syncthreads();

    // pass 1: per-row counts
    if (lds_path) {
        for (int j = t; j < n; j += 256)
            atomicAdd(&cnt[(seg[j].x >> 18) & (BROWS - 1)], 1);
    } else {
        for (int j = beg + t; j < end; j += 256) {
            long long e = cvtmp[j];
            atomicAdd(&cnt[((int)e >> 18) & (BROWS - 1)], 1);
        }
    }
    __syncthreads();

    // exclusive scan of 128 counts on wave 0; also emit rowptr
    if (t < 64) {
        int lane = t;
        int v0 = cnt[lane];
        int v1 = cnt[64 + lane];
        int x0 = v0;
        #pragma unroll
        for (int off = 1; off < 64; off <<= 1) {
            int y = __shfl_up(x0, off, 64);
            if (lane >= off) x0 += y;
        }
        int tot0 = __shfl(x0, 63, 64);
        int x1 = v1;
        #pragma unroll
        for (int off = 1; off < 64; off <<= 1) {
            int y = __shfl_up(x1, off, 64);
            if (lane >= off) x1 += y;
        }
        x1 += tot0;
        int e0 = x0 - v0;
        int e1 = x1 - v1;
        cur[lane] = e0;
        cur[64 + lane] = e1;
        int rowbase = b * BROWS;
        if (rowbase + lane < N_NODES)      rowptr[rowbase + lane] = beg + e0;
        if (rowbase + 64 + lane < N_NODES) rowptr[rowbase + 64 + lane] = beg + e1;
    }
    __syncthreads();

    // pass 2: scatter into row-sorted order; pack (qval<<18)|col
    if (lds_path) {
        for (int j = t; j < n; j += 256) {
            int2 e = seg[j];
            int p = atomicAdd(&cur[(e.x >> 18) & (BROWS - 1)], 1);
            float v = __int_as_float(e.y);
            unsigned int qv = (unsigned int)(v * QSCALE + 0.5f);
            if (qv > 16383u) qv = 16383u;
            cv[beg + p] = (qv << 18) | (unsigned int)(e.x & 0x3FFFF);
        }
    } else {
        for (int j = beg + t; j < end; j += 256) {
            long long e = cvtmp[j];
            int lo = (int)e;
            float v = __int_as_float((int)(e >> 32));
            int p = atomicAdd(&cur[(lo >> 18) & (BROWS - 1)], 1);
            unsigned int qv = (unsigned int)(v * QSCALE + 0.5f);
            if (qv > 16383u) qv = 16383u;
            cv[beg + p] = (qv << 18) | (unsigned int)(lo & 0x3FFFF);
        }
    }
}

// ---------------------------------------------------------------------------
// SpMM over CSR, FP16 tables, FULL-DIM (R4 revert of half-plane split).
// Half-wave-per-edge at stride 2 (both halves share cv lines in-wave),
// 8 gathers of 128 B in flight per half; packed 4-B cv with plain loads;
// fp32 accumulation; cross-half shfl combine; nt y-store (write-once).
// ---------------------------------------------------------------------------
__global__ void spmm_csr(const int* __restrict__ rowptr,
                         const unsigned int* __restrict__ cv,
                         const __half2* __restrict__ x2,
                         __half2* __restrict__ y2) {
    int blk = blockIdx.x;
    int bucket = (blk >> 8) * 8 + (blk & 7);
    int sub = (blk & 255) >> 3;
    int r = bucket * BROWS + sub * 4 + (threadIdx.x >> 6);
    if (r >= N_NODES) return;
    int lane = threadIdx.x & 63;
    int half = lane >> 5;
    int d = lane & 31;
    int beg = rowptr[r];
    int end = rowptr[r + 1];
    float ax0 = 0.0f, ay0 = 0.0f, ax1 = 0.0f, ay1 = 0.0f;
    int j = beg + half;                 // this half's edge stream, stride 2
    for (; j + 14 < end; j += 16) {     // 8 edges per half per iter
        unsigned int u[8];
        __half2 h[8];
        #pragma unroll
        for (int k = 0; k < 8; ++k) u[k] = cv[j + 2 * k];
        #pragma unroll
        for (int k = 0; k < 8; ++k) h[k] = x2[(size_t)(u[k] & 0x3FFFF) * 32 + d];
        #pragma unroll
        for (int k = 0; k < 8; k += 2) {
            float2 f0 = __half22float2(h[k]);
            float2 f1 = __half22float2(h[k + 1]);
            float v0 = (float)(u[k] >> 18) * QINV;
            float v1 = (float)(u[k + 1] >> 18) * QINV;
            ax0 = fmaf(v0, f0.x, ax0); ay0 = fmaf(v0, f0.y, ay0);
            ax1 = fmaf(v1, f1.x, ax1); ay1 = fmaf(v1, f1.y, ay1);
        }
    }
    for (; j + 6 < end; j += 8) {       // 4 edges per half
        unsigned int u0 = cv[j];
        unsigned int u1 = cv[j + 2];
        unsigned int u2 = cv[j + 4];
        unsigned int u3 = cv[j + 6];
        float2 f0 = __half22float2(x2[(size_t)(u0 & 0x3FFFF) * 32 + d]);
        float2 f1 = __half22float2(x2[(size_t)(u1 & 0x3FFFF) * 32 + d]);
        float2 f2 = __half22float2(x2[(size_t)(u2 & 0x3FFFF) * 32 + d]);
        float2 f3 = __half22float2(x2[(size_t)(u3 & 0x3FFFF) * 32 + d]);
        float v0 = (float)(u0 >> 18) * QINV;
        float v1 = (float)(u1 >> 18) * QINV;
        float v2 = (float)(u2 >> 18) * QINV;
        float v3 = (float)(u3 >> 18) * QINV;
        ax0 = fmaf(v0, f0.x, ax0); ay0 = fmaf(v0, f0.y, ay0);
        ax1 = fmaf(v1, f1.x, ax1); ay1 = fmaf(v1, f1.y, ay1);
        ax0 = fmaf(v2, f2.x, ax0); ay0 = fmaf(v2, f2.y, ay0);
        ax1 = fmaf(v3, f3.x, ax1); ay1 = fmaf(v3, f3.y, ay1);
    }
    for (; j < end; j += 2) {
        unsigned int u = cv[j];
        float2 f = __half22float2(x2[(size_t)(u & 0x3FFFF) * 32 + d]);
        float v = (float)(u >> 18) * QINV;
        ax0 = fmaf(v, f.x, ax0); ay0 = fmaf(v, f.y, ay0);
    }
    float ax = ax0 + ax1;
    float ay = ay0 + ay1;
    ax += __shfl_down(ax, 32, 64);
    ay += __shfl_down(ay, 32, 64);
    if (lane < 32) {
        __half2 o = __floats2half2_rn(ax, ay);
        unsigned int ob;
        __builtin_memcpy(&ob, &o, 4);
        __builtin_nontemporal_store(ob, (unsigned int*)&y2[(size_t)r * 32 + d]);
    }
}

// ---------------------------------------------------------------------------
// Layer-3 SpMM restricted to batch rows (~870K edges), same structure,
// fp32 accumulation straight into ACCB (float2 RMW).
// ---------------------------------------------------------------------------
__global__ void spmm_batch(const int* __restrict__ rowptr,
                           const unsigned int* __restrict__ cv,
                           const __half2* __restrict__ x2,
                           const int* __restrict__ users,
                           const int* __restrict__ items,
                           float* __restrict__ accb) {
    int b = blockIdx.x * 4 + (threadIdx.x >> 6);
    if (b >= 2 * BATCH) return;
    int lane = threadIdx.x & 63;
    int half = lane >> 5;
    int d = lane & 31;
    int r = (b < BATCH) ? users[b] : (N_USERS + items[b - BATCH]);
    int beg = rowptr[r];
    int end = rowptr[r + 1];
    float ax0 = 0.0f, ay0 = 0.0f, ax1 = 0.0f, ay1 = 0.0f;
    int j = beg + half;
    for (; j + 14 < end; j += 16) {
        unsigned int u[8];
        __half2 h[8];
        #pragma unroll
        for (int k = 0; k < 8; ++k) u[k] = cv[j + 2 * k];
        #pragma unroll
        for (int k = 0; k < 8; ++k) h[k] = x2[(size_t)(u[k] & 0x3FFFF) * 32 + d];
        #pragma unroll
        for (int k = 0; k < 8; k += 2) {
            float2 f0 = __half22float2(h[k]);
            float2 f1 = __half22float2(h[k + 1]);
            float v0 = (float)(u[k] >> 18) * QINV;
            float v1 = (float)(u[k + 1] >> 18) * QINV;
            ax0 = fmaf(v0, f0.x, ax0); ay0 = fmaf(v0, f0.y, ay0);
            ax1 = fmaf(v1, f1.x, ax1); ay1 = fmaf(v1, f1.y, ay1);
        }
    }
    for (; j + 6 < end; j += 8) {
        unsigned int u0 = cv[j];
        unsigned int u1 = cv[j + 2];
        unsigned int u2 = cv[j + 4];
        unsigned int u3 = cv[j + 6];
        float2 f0 = __half22float2(x2[(size_t)(u0 & 0x3FFFF) * 32 + d]);
        float2 f1 = __half22float2(x2[(size_t)(u1 & 0x3FFFF) * 32 + d]);
        float2 f2 = __half22float2(x2[(size_t)(u2 & 0x3FFFF) * 32 + d]);
        float2 f3 = __half22float2(x2[(size_t)(u3 & 0x3FFFF) * 32 + d]);
        float v0 = (float)(u0 >> 18) * QINV;
        float v1 = (float)(u1 >> 18) * QINV;
        float v2 = (float)(u2 >> 18) * QINV;
        float v3 = (float)(u3 >> 18) * QINV;
        ax0 = fmaf(v0, f0.x, ax0); ay0 = fmaf(v0, f0.y, ay0);
        ax1 = fmaf(v1, f1.x, ax1); ay1 = fmaf(v1, f1.y, ay1);
        ax0 = fmaf(v2, f2.x, ax0); ay0 = fmaf(v2, f2.y, ay0);
        ax1 = fmaf(v3, f3.x, ax1); ay1 = fmaf(v3, f3.y, ay1);
    }
    for (; j < end; j += 2) {
        unsigned int u = cv[j];
        float2 f = __half22float2(x2[(size_t)(u & 0x3FFFF) * 32 + d]);
        float v = (float)(u >> 18) * QINV;
        ax0 = fmaf(v, f.x, ax0); ay0 = fmaf(v, f.y, ay0);
    }
    float ax = ax0 + ax1;
    float ay = ay0 + ay1;
    ax += __shfl_down(ax, 32, 64);
    ay += __shfl_down(ay, 32, 64);
    if (lane < 32) {
        float2* a2 = (float2*)(accb + (size_t)b * 64 + 2 * d);
        float2 o = *a2;
        o.x += ax; o.y += ay;
        *a2 = o;
    }
}

// ---------------------------------------------------------------------------
// Batch accumulator init (fp32 weights -> fp32 ACCB; layer-0 term exact).
// ---------------------------------------------------------------------------
__global__ void batch_init(const float4* __restrict__ uw,
                           const float4* __restrict__ iw,
                           const int* __restrict__ users,
                           const int* __restrict__ items,
                           float4* __restrict__ accb) {
    int tid = blockIdx.x * blockDim.x + threadIdx.x;   // row*16 + q
    const int total = 2 * BATCH * (DIM / 4);
    if (tid >= total) return;
    int r = tid >> 4;
    int q = tid & 15;
    float4 v;
    if (r < BATCH) v = uw[(size_t)users[r] * 16 + q];
    else           v = iw[(size_t)items[r - BATCH] * 16 + q];
    accb[tid] = v;
}

// ---------------------------------------------------------------------------
// Batch accumulator add from fp16 node table (layers 1,2).
// ---------------------------------------------------------------------------
__global__ void batch_add(const __half* __restrict__ emb,
                          const int* __restrict__ users,
                          const int* __restrict__ items,
                          float4* __restrict__ accb) {
    int tid = blockIdx.x * blockDim.x + threadIdx.x;
    const int total = 2 * BATCH * (DIM / 4);
    if (tid >= total) return;
    int r = tid >> 4;
    int q = tid & 15;
    int node = (r < BATCH) ? users[r] : (N_USERS + items[r - BATCH]);
    const __half2* e2 = (const __half2*)(emb + (size_t)node * 64 + q * 4);
    float2 lo = __half22float2(e2[0]);
    float2 hi = __half22float2(e2[1]);
    float4 a = accb[tid];
    a.x += lo.x; a.y += lo.y; a.z += hi.x; a.w += hi.y;
    accb[tid] = a;
}

// ---------------------------------------------------------------------------
// Final dot: out[b] = (accb[b] . accb[BATCH+b]) / 16
// ---------------------------------------------------------------------------
__global__ void final_dot(const float* __restrict__ accb,
                          float* __restrict__ out) {
    int b = blockIdx.x * 4 + (threadIdx.x >> 6);
    int lane = threadIdx.x & 63;
    if (b >= BATCH) return;
    float pu = accb[(size_t)b * 64 + lane];
    float pi = accb[(size_t)(BATCH + b) * 64 + lane];
    float p = pu * pi;
    #pragma unroll
    for (int off = 32; off > 0; off >>= 1)
        p += __shfl_down(p, off, 64);
    if (lane == 0) out[b] = p * (1.0f / 16.0f);
}

extern "C" void kernel_launch(void* const* d_in, const int* in_sizes, int n_in,
                              void* d_out, int out_size, void* d_ws, size_t ws_size,
                              hipStream_t stream) {
    const float* uw   = (const float*)d_in[0];
    const float* iw   = (const float*)d_in[1];
    const float* tw   = (const float*)d_in[2];
    const float* vals = (const float*)d_in[3];
    const int*   row  = (const int*)d_in[4];
    const int*   col  = (const int*)d_in[5];
    const int*   users= (const int*)d_in[6];
    const int*   items= (const int*)d_in[7];
    float* out = (float*)d_out;

    // ---- workspace layout (no aliasing; ~96 MB total) ----
    char* ws = (char*)d_ws;
    const size_t NODE_F = (size_t)N_NODES * DIM;       // 9,664,000 elements
    __half* A     = (__half*)ws; ws += NODE_F * 2;     // 19.33 MB
    __half* B     = (__half*)ws; ws += NODE_F * 2;     // 19.33 MB
    float* ACCB   = (float*)ws;  ws += (size_t)2 * BATCH * DIM * 4;
    int*   bcnt   = (int*)ws;    ws += (size_t)NB * 4;
    int*   bptr   = (int*)ws;    ws += (size_t)(NB + 1) * 4;
    int*   rowptr = (int*)ws;    ws += (size_t)(N_NODES + 1) * 4;
    int*   hcnt   = (int*)ws;    ws += (size_t)NPART * NB * 4;   // 1.21 MB
    unsigned int* cv = (unsigned int*)ws; ws += (size_t)NNZ * 4; // 16 MB packed
    int2*  cvtmp  = (int2*)ws;   ws += (size_t)NNZ * 8;          // 32 MB

    const int node_v4  = N_NODES * (DIM / 4);
    const int batch_v4 = 2 * BATCH * (DIM / 4);

    // ---- layer-0 embedding (fp16) + batch accumulator init (fp32) ----
    concat_init<<<(node_v4 + 255) / 256, 256, 0, stream>>>(
        (const float4*)uw, (const float4*)iw, (const float4*)tw, (__half2*)A);
    batch_init<<<(batch_v4 + 255) / 256, 256, 0, stream>>>(
        (const float4*)uw, (const float4*)iw, users, items, (float4*)ACCB);

    // ---- atomic-free bucketed partition + bucket-local sort -> CSR ----
    part_count<<<NPART, 1024, 0, stream>>>(row, hcnt);
    part_scanA<<<(NB + 3) / 4, 256, 0, stream>>>(hcnt, bcnt);
    part_scanB<<<1, 1024, 0, stream>>>(bcnt, bptr, rowptr);
    part_scatter<<<NPART, 1024, 0, stream>>>(row, col, vals, hcnt, bptr, cvtmp);
    bucket_sort<<<NB, 256, 0, stream>>>(bptr, (const long long*)cvtmp, cv, rowptr);

    // ---- layers 1,2: full SpMM (fp16 tables); layer 3: batch rows only ----
    const int spmm_blocks = ((NB + 7) / 8) * 256;   // 148*256 = 37888
    spmm_csr<<<spmm_blocks, 256, 0, stream>>>(rowptr, cv, (const __half2*)A,
                                              (__half2*)B);
    batch_add<<<(batch_v4 + 255) / 256, 256, 0, stream>>>(
        B, users, items, (float4*)ACCB);
    spmm_csr<<<spmm_blocks, 256, 0, stream>>>(rowptr, cv, (const __half2*)B,
                                              (__half2*)A);
    batch_add<<<(batch_v4 + 255) / 256, 256, 0, stream>>>(
        A, users, items, (float4*)ACCB);
    spmm_batch<<<(2 * BATCH + 3) / 4, 256, 0, stream>>>(
        rowptr, cv, (const __half2*)A, users, items, ACCB);

    final_dot<<<(BATCH + 3) / 4, 256, 0, stream>>>(ACCB, out);
}